// Round 3
// baseline (8386.663 us; speedup 1.0000x reference)
//
#include <hip/hip_runtime.h>
#include <math.h>

// Problem constants
#define B_   128
#define T_   200
#define H_   256
#define E_   256
#define G3   768      // 3*H
#define NGRP 8        // batch groups per direction (16 batch each)
#define NSLC 16       // h-slices per group (16 h-indices each)

__device__ __forceinline__ float sigmoid_(float x) {
  return 1.0f / (1.0f + __expf(-x));
}
__device__ __forceinline__ float tanh_(float x) {
  // 1 - 2/(1+e^{2x}); saturates correctly for |x| large (exp->inf or 0)
  return 1.0f - 2.0f / (1.0f + __expf(2.0f * x));
}

// ---------------------------------------------------------------------------
// Tiled fp32 NT GEMM: C[m][n] = act( sum_k A[m][k]*B[n][k] + bias[n] )
// A: [M][K] row-major (optionally gathered rows: emb[ids[(m&127)*T + (m>>7)]])
// B: [N][K] row-major. Shapes must be multiples of 64 (they are).
// ---------------------------------------------------------------------------
template <int ACT, bool GATHER>
__global__ __launch_bounds__(256) void gemm_nt(
    const float* __restrict__ A, const float* __restrict__ Bw,
    const float* __restrict__ bias, float* __restrict__ C,
    int M, int N, int K, const int* __restrict__ gidx) {
  constexpr int BM = 64, BN = 64, BK = 64;
  __shared__ float As[BK][BM + 4];   // k-major, padded
  __shared__ float Bs[BK][BN + 4];
  const int bm = blockIdx.x * BM, bn = blockIdx.y * BN;
  const int tid = (int)threadIdx.x;
  const int tx = tid & 15, ty = tid >> 4;
  const int lr = tid >> 4;            // load row base (0..15)
  const int lc = (tid & 15) << 2;     // load k-col (0..60)

  const float* arow[4];
#pragma unroll
  for (int i = 0; i < 4; ++i) {
    int r = bm + lr + (i << 4);
    if (GATHER) {
      int src = gidx[(r & (B_ - 1)) * T_ + (r >> 7)];
      arow[i] = A + (size_t)src * K;
    } else {
      arow[i] = A + (size_t)r * K;
    }
  }

  float acc[4][4] = {};
  for (int k0 = 0; k0 < K; k0 += BK) {
#pragma unroll
    for (int i = 0; i < 4; ++i) {
      int rr = lr + (i << 4);
      float4 av = *(const float4*)(arow[i] + k0 + lc);
      As[lc + 0][rr] = av.x; As[lc + 1][rr] = av.y;
      As[lc + 2][rr] = av.z; As[lc + 3][rr] = av.w;
      float4 bv = *(const float4*)(Bw + (size_t)(bn + rr) * K + k0 + lc);
      Bs[lc + 0][rr] = bv.x; Bs[lc + 1][rr] = bv.y;
      Bs[lc + 2][rr] = bv.z; Bs[lc + 3][rr] = bv.w;
    }
    __syncthreads();
#pragma unroll 8
    for (int kk = 0; kk < BK; ++kk) {
      float4 a = *(const float4*)&As[kk][ty << 2];
      float4 b = *(const float4*)&Bs[kk][tx << 2];
      acc[0][0] += a.x * b.x; acc[0][1] += a.x * b.y; acc[0][2] += a.x * b.z; acc[0][3] += a.x * b.w;
      acc[1][0] += a.y * b.x; acc[1][1] += a.y * b.y; acc[1][2] += a.y * b.z; acc[1][3] += a.y * b.w;
      acc[2][0] += a.z * b.x; acc[2][1] += a.z * b.y; acc[2][2] += a.z * b.z; acc[2][3] += a.z * b.w;
      acc[3][0] += a.w * b.x; acc[3][1] += a.w * b.y; acc[3][2] += a.w * b.z; acc[3][3] += a.w * b.w;
    }
    __syncthreads();
  }

  float4 bb = *(const float4*)&bias[bn + (tx << 2)];
#pragma unroll
  for (int i = 0; i < 4; ++i) {
    int m = bm + (ty << 2) + i;
    float4 o;
    o.x = acc[i][0] + bb.x; o.y = acc[i][1] + bb.y;
    o.z = acc[i][2] + bb.z; o.w = acc[i][3] + bb.w;
    if (ACT == 1) {
      o.x = tanh_(o.x); o.y = tanh_(o.y); o.z = tanh_(o.z); o.w = tanh_(o.w);
    }
    *(float4*)&C[(size_t)m * N + bn + (tx << 2)] = o;
  }
}

// ---------------------------------------------------------------------------
// 512x512 transpose (W_word -> W_word^T) so attention GEMM is NT-form
// ---------------------------------------------------------------------------
__global__ __launch_bounds__(256) void transpose512(
    const float* __restrict__ in, float* __restrict__ out) {
  __shared__ float t[32][33];
  int bx = blockIdx.x * 32, by = blockIdx.y * 32;
  int c = (int)threadIdx.x & 31, r8 = (int)threadIdx.x >> 5;
#pragma unroll
  for (int i = 0; i < 4; ++i)
    t[r8 + i * 8][c] = in[(size_t)(by + r8 + i * 8) * 512 + bx + c];
  __syncthreads();
#pragma unroll
  for (int i = 0; i < 4; ++i)
    out[(size_t)(bx + r8 + i * 8) * 512 + by + c] = t[c][r8 + i * 8];
}

// ---------------------------------------------------------------------------
// Bidirectional GRU scan. Grid = 256 blocks, remapped for XCD affinity:
//   bid = slice*16 + dg,  dg = dir*8 + grp  (group members share bid%8 -> XCD)
// Block owns 16 batches x 16 h-slice x 3 gates = 768 outputs/step.
// w_hh slice is REGISTER-RESIDENT: 48 rows x 256 = 12288 floats / 256 threads
// = 48 floats (3 gates x 16 float4) per thread, loaded once before the t-loop.
// k=256 reduction is c-split across the 4 waves (each wave one 64-float
// quarter); per-lane register tile = 4 batches x 1 j x 3 gates. Cross-wave
// reduction via 12KB LDS scratch. h exchanged per step via global double
// buffer + per-group release/acquire counter (agent scope).
// LDS total = 28KB. VGPR ~240 (launch_bounds(256,1) lifts cap to 512).
// ---------------------------------------------------------------------------
__global__ __launch_bounds__(256, 1) void gru_scan(
    const float* __restrict__ gi,        // [2][T][B][768]
    const float* __restrict__ w_hh_f, const float* __restrict__ w_hh_b,
    const float* __restrict__ b_hh_f, const float* __restrict__ b_hh_b,
    float* __restrict__ h_ex,            // [2 parity][2 dir][B][H]
    int* __restrict__ cnt,               // [16 groups][256]
    float* __restrict__ outw,            // [T*B][512]
    float* __restrict__ state_out)       // [2][B][H]
{
  __shared__ float  hlds[16][256];       // 16KB, XOR-swizzled by batch row
  __shared__ float4 pscr[4 * 64 * 3];    // 12KB partials: [wave][lane][gate]

  const int bid = (int)blockIdx.x;
  const int slice = bid >> 4;            // 0..15
  const int dg = bid & 15;               // dir*8 + grp
  const int dir = dg >> 3, grp = dg & 7;
  const int tid = (int)threadIdx.x;
  const int lane = tid & 63, wv = tid >> 6;
  const int j = tid & 15;                // worker j == finalize j
  const int bq = lane >> 4;              // worker batch-quad (0..3)
  const int fb = tid >> 4;               // finalize batch (0..15)
  const int j0 = slice * 16;
  const int hk = j0 + j;                 // global h index of this output
  const int gb = grp * 16 + fb;          // global batch of this output
  const float* whh = dir ? w_hh_b : w_hh_f;
  const float* bhh = dir ? b_hh_b : b_hh_f;

  // --- load this thread's w_hh tile into registers (once) ---
  // rows {0,1,2}*H + hk (gates r,z,n), columns [wv*64 .. wv*64+63]
  float4 wr_[16], wz_[16], wn_[16];
  {
    const float* base_r = whh + (size_t)(0 * H_ + hk) * H_ + (wv << 6);
    const float* base_z = whh + (size_t)(1 * H_ + hk) * H_ + (wv << 6);
    const float* base_n = whh + (size_t)(2 * H_ + hk) * H_ + (wv << 6);
#pragma unroll
    for (int ci = 0; ci < 16; ++ci) {
      wr_[ci] = *(const float4*)(base_r + (ci << 2));
      wz_[ci] = *(const float4*)(base_z + (ci << 2));
      wn_[ci] = *(const float4*)(base_n + (ci << 2));
    }
  }
  const float bh_r = bhh[hk];
  const float bh_z = bhh[H_ + hk];
  const float bh_n = bhh[2 * H_ + hk];
  int* mycnt = cnt + dg * 256;
  const size_t dirTB = (size_t)dir * T_ * B_;

  for (int t = 0; t < T_; ++t) {
    const int par = t & 1;
    const float* hsrc = h_ex + ((size_t)(par * 2 + dir) * B_) * H_;
    // stage group's h[16][256] into LDS (swizzled)
    for (int q = tid; q < 16 * 64; q += 256) {
      int bb = q >> 6, c4 = q & 63;
      float4 v = *(const float4*)&hsrc[(size_t)(grp * 16 + bb) * H_ + (c4 << 2)];
      *(float4*)&hlds[bb][(c4 ^ bb) << 2] = v;
    }
    // gi loads for this thread's output (consumed after reduction barrier)
    const int ta = dir ? (T_ - 1 - t) : t;
    const float* girow = gi + (dirTB + (size_t)ta * B_ + gb) * G3;
    const float gi_r = girow[hk];
    const float gi_z = girow[H_ + hk];
    const float gi_n = girow[2 * H_ + hk];
    __syncthreads();   // B1: hlds ready

    // --- worker phase: partial dots over this wave's c-quarter ---
    float pr[4] = {0.f, 0.f, 0.f, 0.f};
    float pz[4] = {0.f, 0.f, 0.f, 0.f};
    float pn[4] = {0.f, 0.f, 0.f, 0.f};
    const int cbase = wv << 4;
#pragma unroll
    for (int ci = 0; ci < 16; ++ci) {
      const int cc = cbase + ci;
      const float4 wr4 = wr_[ci];
      const float4 wz4 = wz_[ci];
      const float4 wn4 = wn_[ci];
#pragma unroll
      for (int k = 0; k < 4; ++k) {
        const int hb = (bq << 2) + k;
        const float4 h4 = *(const float4*)&hlds[hb][(cc ^ hb) << 2];
        pr[k] += h4.x * wr4.x + h4.y * wr4.y + h4.z * wr4.z + h4.w * wr4.w;
        pz[k] += h4.x * wz4.x + h4.y * wz4.y + h4.z * wz4.z + h4.w * wz4.w;
        pn[k] += h4.x * wn4.x + h4.y * wn4.y + h4.z * wn4.z + h4.w * wn4.w;
      }
    }
    const int wl3 = (wv * 64 + lane) * 3;
    pscr[wl3 + 0] = make_float4(pr[0], pr[1], pr[2], pr[3]);
    pscr[wl3 + 1] = make_float4(pz[0], pz[1], pz[2], pz[3]);
    pscr[wl3 + 2] = make_float4(pn[0], pn[1], pn[2], pn[3]);
    __syncthreads();   // B2: partials ready

    // --- finalize phase: thread owns output (gb, hk) ---
    const int ls = ((fb >> 2) << 4) + j;   // worker lane holding our partials
    const int kk = fb & 3;
    const float* ps = (const float*)pscr;
    float ar = 0.f, az = 0.f, an = 0.f;
#pragma unroll
    for (int w = 0; w < 4; ++w) {
      const int basef = ((w * 64 + ls) * 3) << 2;
      ar += ps[basef + kk];
      az += ps[basef + 4 + kk];
      an += ps[basef + 8 + kk];
    }
    const float hprev = hlds[fb][(((hk >> 2) ^ fb) << 2) + (hk & 3)];
    const float r = sigmoid_(gi_r + ar + bh_r);
    const float z = sigmoid_(gi_z + az + bh_z);
    const float nv = tanh_(gi_n + r * (an + bh_n));
    const float hnew = (1.0f - z) * nv + z * hprev;

    float* hdst = h_ex + ((size_t)((par ^ 1) * 2 + dir) * B_) * H_;
    hdst[(size_t)gb * H_ + hk] = hnew;
    outw[((size_t)ta * B_ + gb) * 512 + dir * H_ + hk] = hnew;
    if (t == T_ - 1)
      state_out[(size_t)(dir * B_ + gb) * H_ + hk] = hnew;

    if (t < T_ - 1) {
      __syncthreads();  // B3: all waves' stores drained (implied vmcnt(0))
      if (tid == 0) {
        __threadfence();
        __hip_atomic_fetch_add(&mycnt[t + 1], 1, __ATOMIC_RELEASE,
                               __HIP_MEMORY_SCOPE_AGENT);
        while (__hip_atomic_load(&mycnt[t + 1], __ATOMIC_ACQUIRE,
                                 __HIP_MEMORY_SCOPE_AGENT) < NSLC) {}
      }
      __syncthreads();  // B4: whole block waits for group arrival
    }
  }
}

// ---------------------------------------------------------------------------
// logits[m] = squish[m][:512] . proj[:512]   (one wave per row)
// ---------------------------------------------------------------------------
__global__ __launch_bounds__(256) void logits_k(
    const float* __restrict__ squish, const float* __restrict__ proj,
    float* __restrict__ attn) {
  int wid = (int)threadIdx.x >> 6, lane = (int)threadIdx.x & 63;
  int m = (int)blockIdx.x * 4 + wid;
  const float* row = squish + (size_t)m * 512;
  int k = lane << 3;
  float4 a0 = *(const float4*)&row[k],  a1 = *(const float4*)&row[k + 4];
  float4 p0 = *(const float4*)&proj[k], p1 = *(const float4*)&proj[k + 4];
  float s = a0.x * p0.x + a0.y * p0.y + a0.z * p0.z + a0.w * p0.w +
            a1.x * p1.x + a1.y * p1.y + a1.z * p1.z + a1.w * p1.w;
#pragma unroll
  for (int o = 32; o; o >>= 1) s += __shfl_down(s, o);
  if (lane == 0) attn[m] = s;
}

// ---------------------------------------------------------------------------
// Per-batch softmax over T + weighted sum -> sent_vectors, attn_norm
// ---------------------------------------------------------------------------
__global__ __launch_bounds__(256) void attnsv_k(
    const float* __restrict__ logit, const float* __restrict__ outw,
    float* __restrict__ sent, float* __restrict__ attn_out) {
  __shared__ float red[256];
  __shared__ float wt[T_];
  const int b = (int)blockIdx.x, tid = (int)threadIdx.x;
  float lg = (tid < T_) ? logit[tid * B_ + b] : -INFINITY;
  red[tid] = lg; __syncthreads();
#pragma unroll
  for (int o = 128; o; o >>= 1) {
    if (tid < o) red[tid] = fmaxf(red[tid], red[tid + o]);
    __syncthreads();
  }
  float mx = red[0]; __syncthreads();
  float e = (tid < T_) ? __expf(lg - mx) : 0.0f;
  red[tid] = e; __syncthreads();
#pragma unroll
  for (int o = 128; o; o >>= 1) {
    if (tid < o) red[tid] += red[tid + o];
    __syncthreads();
  }
  float inv = 1.0f / red[0];
  if (tid < T_) {
    float w = e * inv;
    wt[tid] = w;
    attn_out[b * T_ + tid] = w;
  }
  __syncthreads();
  int c = tid * 2;
  float s0 = 0.f, s1 = 0.f;
  for (int t = 0; t < T_; ++t) {
    float w = wt[t];
    float2 v = *(const float2*)&outw[((size_t)t * B_ + b) * 512 + c];
    s0 += w * v.x; s1 += w * v.y;
  }
  *(float2*)&sent[b * 512 + c] = make_float2(s0, s1);
}

// ---------------------------------------------------------------------------
extern "C" void kernel_launch(void* const* d_in, const int* in_sizes, int n_in,
                              void* d_out, int out_size, void* d_ws, size_t ws_size,
                              hipStream_t stream) {
  const int*   ids     = (const int*)d_in[0];
  const float* state_w = (const float*)d_in[1];
  const float* emb     = (const float*)d_in[2];
  const float* w_ih_f  = (const float*)d_in[3];
  const float* w_hh_f  = (const float*)d_in[4];
  const float* b_ih_f  = (const float*)d_in[5];
  const float* b_hh_f  = (const float*)d_in[6];
  const float* w_ih_b  = (const float*)d_in[7];
  const float* w_hh_b  = (const float*)d_in[8];
  const float* b_ih_b  = (const float*)d_in[9];
  const float* b_hh_b  = (const float*)d_in[10];
  const float* W_word  = (const float*)d_in[11];
  const float* b_word  = (const float*)d_in[12];
  const float* proj    = (const float*)d_in[13];
  float* out = (float*)d_out;

  // Workspace layout (floats). Peak ~211.4 MB.
  float* w = (float*)d_ws;
  const size_t GI_DIR = (size_t)T_ * B_ * G3;         // 19,660,800
  float* gi     = w;                                  // [2][T][B][768]
  float* outw   = w + 2 * GI_DIR;                     // [T*B][512]
  float* wT     = outw + (size_t)T_ * B_ * 512;       // [512][512]
  float* h_ex   = wT + 512 * 512;                     // [2][2][B][H]
  int*   cnt    = (int*)(h_ex + 2 * 2 * B_ * H_);     // [16][256]
  float* logits = (float*)(cnt + 16 * 256);           // [T*B]
  float* squish = w;                                  // alias over gi (dead after scan)

  // init: zero barrier counters, copy initial hidden state
  hipMemsetAsync(cnt, 0, 16 * 256 * sizeof(int), stream);
  hipMemcpyAsync(h_ex, state_w, 2 * B_ * H_ * sizeof(float),
                 hipMemcpyDeviceToDevice, stream);

  // W_word^T for NT GEMM
  transpose512<<<dim3(16, 16), 256, 0, stream>>>(W_word, wT);

  // gi = gather(emb, ids) @ w_ih^T + b_ih  (both directions)
  gemm_nt<0, true><<<dim3(400, 12), 256, 0, stream>>>(
      emb, w_ih_f, b_ih_f, gi, T_ * B_, G3, E_, ids);
  gemm_nt<0, true><<<dim3(400, 12), 256, 0, stream>>>(
      emb, w_ih_b, b_ih_b, gi + GI_DIR, T_ * B_, G3, E_, ids);

  // recurrent scan (both directions, persistent blocks)
  gru_scan<<<dim3(256), 256, 0, stream>>>(
      gi, w_hh_f, w_hh_b, b_hh_f, b_hh_b, h_ex, cnt, outw,
      out + B_ * 512 /* state_out at offset 65536 */);

  // squish = tanh(outw @ W_word + b_word)
  gemm_nt<1, false><<<dim3(400, 8), 256, 0, stream>>>(
      outw, wT, b_word, squish, T_ * B_, 512, 512, nullptr);

  // logits = squish @ proj
  logits_k<<<dim3(6400), 256, 0, stream>>>(squish, proj, logits);

  // softmax over T + weighted sum
  attnsv_k<<<dim3(B_), 256, 0, stream>>>(
      logits, outw, out /* sent at 0 */, out + 2 * B_ * 512 /* attn at 131072 */);

  (void)in_sizes; (void)n_in; (void)out_size; (void)ws_size;
}

// Round 6
// 4332.819 us; speedup vs baseline: 1.9356x; 1.9356x over previous
//
#include <hip/hip_runtime.h>
#include <math.h>

// Problem constants
#define B_   128
#define T_   200
#define H_   256
#define E_   256
#define G3   768      // 3*H
#define NBG  32       // batch groups per direction (4 batches each)
#define NQ   4        // j-quads (64 h-indices each); rendezvous width

// clang vector type for nontemporal builtins (HIP float4 is a class type
// that __builtin_nontemporal_load rejects; this alias is layout-identical)
typedef float f32x4 __attribute__((ext_vector_type(4)));

__device__ __forceinline__ float sigmoid_(float x) {
  return 1.0f / (1.0f + __expf(-x));
}
__device__ __forceinline__ float tanh_(float x) {
  return 1.0f - 2.0f / (1.0f + __expf(2.0f * x));
}

// ---------------------------------------------------------------------------
// Tiled fp32 NT GEMM: C[m][n] = act( sum_k A[m][k]*B[n][k] + bias[n] )
// (unchanged from r3 — measured correct)
// ---------------------------------------------------------------------------
template <int ACT, bool GATHER>
__global__ __launch_bounds__(256) void gemm_nt(
    const float* __restrict__ A, const float* __restrict__ Bw,
    const float* __restrict__ bias, float* __restrict__ C,
    int M, int N, int K, const int* __restrict__ gidx) {
  constexpr int BM = 64, BN = 64, BK = 64;
  __shared__ float As[BK][BM + 4];
  __shared__ float Bs[BK][BN + 4];
  const int bm = blockIdx.x * BM, bn = blockIdx.y * BN;
  const int tid = (int)threadIdx.x;
  const int tx = tid & 15, ty = tid >> 4;
  const int lr = tid >> 4;
  const int lc = (tid & 15) << 2;

  const float* arow[4];
#pragma unroll
  for (int i = 0; i < 4; ++i) {
    int r = bm + lr + (i << 4);
    if (GATHER) {
      int src = gidx[(r & (B_ - 1)) * T_ + (r >> 7)];
      arow[i] = A + (size_t)src * K;
    } else {
      arow[i] = A + (size_t)r * K;
    }
  }

  float acc[4][4] = {};
  for (int k0 = 0; k0 < K; k0 += BK) {
#pragma unroll
    for (int i = 0; i < 4; ++i) {
      int rr = lr + (i << 4);
      float4 av = *(const float4*)(arow[i] + k0 + lc);
      As[lc + 0][rr] = av.x; As[lc + 1][rr] = av.y;
      As[lc + 2][rr] = av.z; As[lc + 3][rr] = av.w;
      float4 bv = *(const float4*)(Bw + (size_t)(bn + rr) * K + k0 + lc);
      Bs[lc + 0][rr] = bv.x; Bs[lc + 1][rr] = bv.y;
      Bs[lc + 2][rr] = bv.z; Bs[lc + 3][rr] = bv.w;
    }
    __syncthreads();
#pragma unroll 8
    for (int kk = 0; kk < BK; ++kk) {
      float4 a = *(const float4*)&As[kk][ty << 2];
      float4 b = *(const float4*)&Bs[kk][tx << 2];
      acc[0][0] += a.x * b.x; acc[0][1] += a.x * b.y; acc[0][2] += a.x * b.z; acc[0][3] += a.x * b.w;
      acc[1][0] += a.y * b.x; acc[1][1] += a.y * b.y; acc[1][2] += a.y * b.z; acc[1][3] += a.y * b.w;
      acc[2][0] += a.z * b.x; acc[2][1] += a.z * b.y; acc[2][2] += a.z * b.z; acc[2][3] += a.z * b.w;
      acc[3][0] += a.w * b.x; acc[3][1] += a.w * b.y; acc[3][2] += a.w * b.z; acc[3][3] += a.w * b.w;
    }
    __syncthreads();
  }

  float4 bb = *(const float4*)&bias[bn + (tx << 2)];
#pragma unroll
  for (int i = 0; i < 4; ++i) {
    int m = bm + (ty << 2) + i;
    float4 o;
    o.x = acc[i][0] + bb.x; o.y = acc[i][1] + bb.y;
    o.z = acc[i][2] + bb.z; o.w = acc[i][3] + bb.w;
    if (ACT == 1) {
      o.x = tanh_(o.x); o.y = tanh_(o.y); o.z = tanh_(o.z); o.w = tanh_(o.w);
    }
    *(float4*)&C[(size_t)m * N + bn + (tx << 2)] = o;
  }
}

// ---------------------------------------------------------------------------
// 512x512 transpose (W_word -> W_word^T)
// ---------------------------------------------------------------------------
__global__ __launch_bounds__(256) void transpose512(
    const float* __restrict__ in, float* __restrict__ out) {
  __shared__ float t[32][33];
  int bx = blockIdx.x * 32, by = blockIdx.y * 32;
  int c = (int)threadIdx.x & 31, r8 = (int)threadIdx.x >> 5;
#pragma unroll
  for (int i = 0; i < 4; ++i)
    t[r8 + i * 8][c] = in[(size_t)(by + r8 + i * 8) * 512 + bx + c];
  __syncthreads();
#pragma unroll
  for (int i = 0; i < 4; ++i)
    out[(size_t)(bx + r8 + i * 8) * 512 + by + c] = t[c][r8 + i * 8];
}

// ---------------------------------------------------------------------------
// Bidirectional GRU scan, v2 topology (r6 = r5 + compile fix).
// Grid = 256 blocks: bid = quad*64 + dir*32 + bg
//   -> the 4 rendezvous partners (j-quads of one (dir,4-batch-group)) share
//      bid%8, i.e. one XCD under round-robin dispatch.
// Block owns 4 batches x 64 j (one quad) x 3 gates = 768 outputs/step.
// w_hh tile register-resident: 192 floats/thread (3 gates x 64-c quarter).
// Worker thread (wv=c-quarter, lane=j): hlds reads are wave-uniform
// broadcasts (conflict-free). Cross-quarter reduce via padded pscr.
// Sync: per-(group,quad,t) FLAG, single release-store by tid0; 3 partner
// flags polled in parallel by waves 1-3 lane 0 with s_sleep throttle.
// No atomic RMW anywhere in the step loop.
// ---------------------------------------------------------------------------
__global__ __launch_bounds__(256, 1) void gru_scan(
    const float* __restrict__ gi,        // [2][T][B][768]
    const float* __restrict__ w_hh_f, const float* __restrict__ w_hh_b,
    const float* __restrict__ b_hh_f, const float* __restrict__ b_hh_b,
    float* __restrict__ h_ex,            // [2 parity][2 dir][B][H]
    int* __restrict__ flg,               // [2*32 groups][4 quads][256]
    float* __restrict__ outw,            // [T*B][512]
    float* __restrict__ state_out)       // [2][B][H]
{
  __shared__ float hlds[4][256];         // 4KB: h for the group's 4 batches
  __shared__ float pscr[4][64][13];      // 13.3KB padded partials

  const int bid = (int)blockIdx.x;
  const int myq = bid >> 6;              // j-quad 0..3
  const int dgb = bid & 63;              // dir*32 + bg
  const int dir = dgb >> 5, bg = dgb & 31;
  const int tid = (int)threadIdx.x;
  const int lane = tid & 63;             // j within quad (worker & finalize)
  const int wv = tid >> 6;               // worker: c-quarter; finalize: batch
  const int jg = (myq << 6) + lane;      // global h index of this output
  const int gb = (bg << 2) + wv;         // finalize: global batch
  const float* whh = dir ? w_hh_b : w_hh_f;
  const float* bhh = dir ? b_hh_b : b_hh_f;

  // --- register w tile: rows g*H+jg, cols [wv*64, wv*64+64) ---
  float4 wr_[16], wz_[16], wn_[16];
  {
    const float* base_r = whh + (size_t)(0 * H_ + jg) * H_ + (wv << 6);
    const float* base_z = whh + (size_t)(1 * H_ + jg) * H_ + (wv << 6);
    const float* base_n = whh + (size_t)(2 * H_ + jg) * H_ + (wv << 6);
#pragma unroll
    for (int ci = 0; ci < 16; ++ci) {
      wr_[ci] = *(const float4*)(base_r + (ci << 2));
      wz_[ci] = *(const float4*)(base_z + (ci << 2));
      wn_[ci] = *(const float4*)(base_n + (ci << 2));
    }
  }
  const float bh_r = bhh[jg];
  const float bh_z = bhh[H_ + jg];
  const float bh_n = bhh[2 * H_ + jg];

  int* myflag   = flg + ((dgb << 2) + myq) * 256;
  int* pollflag = flg + ((dgb << 2) + ((myq + wv) & 3)) * 256;  // waves 1..3
  const size_t dirTB = (size_t)dir * T_ * B_;

  for (int t = 0; t < T_; ++t) {
    // --- wait for the 3 partner quads' h of step t-1 (parallel polls) ---
    if (t > 0 && wv > 0 && lane == 0) {
      while (__hip_atomic_load(&pollflag[t - 1], __ATOMIC_ACQUIRE,
                               __HIP_MEMORY_SCOPE_AGENT) == 0) {
        __builtin_amdgcn_s_sleep(2);
      }
    }
    __syncthreads();   // join polls

    const int par = t & 1;
    const float* hsrc = h_ex + ((size_t)(par * 2 + dir) * B_) * H_;
    // stage h[4 batches][256] (1 float4/thread, L1-bypass via nt load)
    {
      int b4 = tid >> 6, c4 = tid & 63;
      f32x4 v = __builtin_nontemporal_load(
          (const f32x4*)&hsrc[(size_t)((bg << 2) + b4) * H_ + (c4 << 2)]);
      *(f32x4*)&hlds[b4][c4 << 2] = v;
    }
    // gi loads for this thread's output (gb, jg), consumed in finalize
    const int ta = dir ? (T_ - 1 - t) : t;
    const float* girow = gi + (dirTB + (size_t)ta * B_ + gb) * G3;
    const float gi_r = girow[jg];
    const float gi_z = girow[H_ + jg];
    const float gi_n = girow[2 * H_ + jg];
    __syncthreads();   // hlds ready

    // --- worker: partial dots over this wave's c-quarter, 4 batches ---
    float pr[4] = {0.f, 0.f, 0.f, 0.f};
    float pz[4] = {0.f, 0.f, 0.f, 0.f};
    float pn[4] = {0.f, 0.f, 0.f, 0.f};
#pragma unroll
    for (int ci = 0; ci < 16; ++ci) {
      const int co = (wv << 6) + (ci << 2);
      const float4 wr4 = wr_[ci];
      const float4 wz4 = wz_[ci];
      const float4 wn4 = wn_[ci];
#pragma unroll
      for (int k = 0; k < 4; ++k) {
        const float4 h4 = *(const float4*)&hlds[k][co];   // broadcast
        pr[k] += h4.x * wr4.x + h4.y * wr4.y + h4.z * wr4.z + h4.w * wr4.w;
        pz[k] += h4.x * wz4.x + h4.y * wz4.y + h4.z * wz4.z + h4.w * wz4.w;
        pn[k] += h4.x * wn4.x + h4.y * wn4.y + h4.z * wn4.z + h4.w * wn4.w;
      }
    }
#pragma unroll
    for (int k = 0; k < 4; ++k) {
      pscr[wv][lane][k]     = pr[k];
      pscr[wv][lane][4 + k] = pz[k];
      pscr[wv][lane][8 + k] = pn[k];
    }
    __syncthreads();   // partials ready

    // --- finalize: thread owns output (batch wv -> gb, j = lane -> jg) ---
    float ar = 0.f, az = 0.f, an = 0.f;
#pragma unroll
    for (int q = 0; q < 4; ++q) {
      ar += pscr[q][lane][wv];
      az += pscr[q][lane][4 + wv];
      an += pscr[q][lane][8 + wv];
    }
    const float hprev = hlds[wv][jg];
    const float r = sigmoid_(gi_r + ar + bh_r);
    const float z = sigmoid_(gi_z + az + bh_z);
    const float nv = tanh_(gi_n + r * (an + bh_n));
    const float hnew = (1.0f - z) * nv + z * hprev;

    float* hdst = h_ex + ((size_t)((par ^ 1) * 2 + dir) * B_) * H_;
    hdst[(size_t)gb * H_ + jg] = hnew;
    outw[((size_t)ta * B_ + gb) * 512 + dir * H_ + jg] = hnew;
    if (t == T_ - 1)
      state_out[(size_t)(dir * B_ + gb) * H_ + jg] = hnew;

    if (t < T_ - 1) {
      __syncthreads();  // all waves' h stores drained (vmcnt(0) at barrier)
      if (tid == 0) {
        __threadfence();                       // agent visibility of h stores
        __hip_atomic_store(&myflag[t], 1, __ATOMIC_RELEASE,
                           __HIP_MEMORY_SCOPE_AGENT);
      }
    }
  }
}

// ---------------------------------------------------------------------------
// logits[m] = squish[m][:512] . proj[:512]
// ---------------------------------------------------------------------------
__global__ __launch_bounds__(256) void logits_k(
    const float* __restrict__ squish, const float* __restrict__ proj,
    float* __restrict__ attn) {
  int wid = (int)threadIdx.x >> 6, lane = (int)threadIdx.x & 63;
  int m = (int)blockIdx.x * 4 + wid;
  const float* row = squish + (size_t)m * 512;
  int k = lane << 3;
  float4 a0 = *(const float4*)&row[k],  a1 = *(const float4*)&row[k + 4];
  float4 p0 = *(const float4*)&proj[k], p1 = *(const float4*)&proj[k + 4];
  float s = a0.x * p0.x + a0.y * p0.y + a0.z * p0.z + a0.w * p0.w +
            a1.x * p1.x + a1.y * p1.y + a1.z * p1.z + a1.w * p1.w;
#pragma unroll
  for (int o = 32; o; o >>= 1) s += __shfl_down(s, o);
  if (lane == 0) attn[m] = s;
}

// ---------------------------------------------------------------------------
// Per-batch softmax over T + weighted sum
// ---------------------------------------------------------------------------
__global__ __launch_bounds__(256) void attnsv_k(
    const float* __restrict__ logit, const float* __restrict__ outw,
    float* __restrict__ sent, float* __restrict__ attn_out) {
  __shared__ float red[256];
  __shared__ float wt[T_];
  const int b = (int)blockIdx.x, tid = (int)threadIdx.x;
  float lg = (tid < T_) ? logit[tid * B_ + b] : -INFINITY;
  red[tid] = lg; __syncthreads();
#pragma unroll
  for (int o = 128; o; o >>= 1) {
    if (tid < o) red[tid] = fmaxf(red[tid], red[tid + o]);
    __syncthreads();
  }
  float mx = red[0]; __syncthreads();
  float e = (tid < T_) ? __expf(lg - mx) : 0.0f;
  red[tid] = e; __syncthreads();
#pragma unroll
  for (int o = 128; o; o >>= 1) {
    if (tid < o) red[tid] += red[tid + o];
    __syncthreads();
  }
  float inv = 1.0f / red[0];
  if (tid < T_) {
    float w = e * inv;
    wt[tid] = w;
    attn_out[b * T_ + tid] = w;
  }
  __syncthreads();
  int c = tid * 2;
  float s0 = 0.f, s1 = 0.f;
  for (int t = 0; t < T_; ++t) {
    float w = wt[t];
    float2 v = *(const float2*)&outw[((size_t)t * B_ + b) * 512 + c];
    s0 += w * v.x; s1 += w * v.y;
  }
  *(float2*)&sent[b * 512 + c] = make_float2(s0, s1);
}

// ---------------------------------------------------------------------------
extern "C" void kernel_launch(void* const* d_in, const int* in_sizes, int n_in,
                              void* d_out, int out_size, void* d_ws, size_t ws_size,
                              hipStream_t stream) {
  const int*   ids     = (const int*)d_in[0];
  const float* state_w = (const float*)d_in[1];
  const float* emb     = (const float*)d_in[2];
  const float* w_ih_f  = (const float*)d_in[3];
  const float* w_hh_f  = (const float*)d_in[4];
  const float* b_ih_f  = (const float*)d_in[5];
  const float* b_hh_f  = (const float*)d_in[6];
  const float* w_ih_b  = (const float*)d_in[7];
  const float* w_hh_b  = (const float*)d_in[8];
  const float* b_ih_b  = (const float*)d_in[9];
  const float* b_hh_b  = (const float*)d_in[10];
  const float* W_word  = (const float*)d_in[11];
  const float* b_word  = (const float*)d_in[12];
  const float* proj    = (const float*)d_in[13];
  float* out = (float*)d_out;

  // Workspace layout (floats).
  float* w = (float*)d_ws;
  const size_t GI_DIR = (size_t)T_ * B_ * G3;         // 19,660,800
  float* gi     = w;                                  // [2][T][B][768]
  float* outw   = w + 2 * GI_DIR;                     // [T*B][512]
  float* wT     = outw + (size_t)T_ * B_ * 512;       // [512][512]
  float* h_ex   = wT + 512 * 512;                     // [2][2][B][H]
  int*   flg    = (int*)(h_ex + 2 * 2 * B_ * H_);     // [64 grp][4 q][256]
  float* logits = (float*)(flg + 64 * 4 * 256);       // [T*B]
  float* squish = w;                                  // alias over gi

  // init: zero flags (ws is 0xAA-poisoned each launch!), copy initial h
  (void)hipMemsetAsync(flg, 0, 64 * 4 * 256 * sizeof(int), stream);
  (void)hipMemcpyAsync(h_ex, state_w, 2 * B_ * H_ * sizeof(float),
                       hipMemcpyDeviceToDevice, stream);

  transpose512<<<dim3(16, 16), 256, 0, stream>>>(W_word, wT);

  gemm_nt<0, true><<<dim3(400, 12), 256, 0, stream>>>(
      emb, w_ih_f, b_ih_f, gi, T_ * B_, G3, E_, ids);
  gemm_nt<0, true><<<dim3(400, 12), 256, 0, stream>>>(
      emb, w_ih_b, b_ih_b, gi + GI_DIR, T_ * B_, G3, E_, ids);

  gru_scan<<<dim3(256), 256, 0, stream>>>(
      gi, w_hh_f, w_hh_b, b_hh_f, b_hh_b, h_ex, flg, outw,
      out + B_ * 512 /* state_out at offset 65536 */);

  gemm_nt<1, false><<<dim3(400, 8), 256, 0, stream>>>(
      outw, wT, b_word, squish, T_ * B_, 512, 512, nullptr);

  logits_k<<<dim3(6400), 256, 0, stream>>>(squish, proj, logits);

  attnsv_k<<<dim3(B_), 256, 0, stream>>>(
      logits, outw, out /* sent */, out + 2 * B_ * 512 /* attn */);

  (void)in_sizes; (void)n_in; (void)out_size; (void)ws_size;
}

// Round 7
// 1882.236 us; speedup vs baseline: 4.4557x; 2.3020x over previous
//
#include <hip/hip_runtime.h>
#include <math.h>

// Problem constants
#define B_   128
#define T_   200
#define H_   256
#define E_   256
#define G3   768      // 3*H
#define NBG  32       // batch groups per direction (4 batches each)
#define NQ   4        // j-quads (64 h-indices each); rendezvous width

typedef float f32x4 __attribute__((ext_vector_type(4)));

__device__ __forceinline__ float sigmoid_(float x) {
  return 1.0f / (1.0f + __expf(-x));
}
__device__ __forceinline__ float tanh_(float x) {
  return 1.0f - 2.0f / (1.0f + __expf(2.0f * x));
}

// ---------------------------------------------------------------------------
// Tiled fp32 NT GEMM: C[m][n] = act( sum_k A[m][k]*B[n][k] + bias[n] )
// (unchanged from r3 — measured correct)
// ---------------------------------------------------------------------------
template <int ACT, bool GATHER>
__global__ __launch_bounds__(256) void gemm_nt(
    const float* __restrict__ A, const float* __restrict__ Bw,
    const float* __restrict__ bias, float* __restrict__ C,
    int M, int N, int K, const int* __restrict__ gidx) {
  constexpr int BM = 64, BN = 64, BK = 64;
  __shared__ float As[BK][BM + 4];
  __shared__ float Bs[BK][BN + 4];
  const int bm = blockIdx.x * BM, bn = blockIdx.y * BN;
  const int tid = (int)threadIdx.x;
  const int tx = tid & 15, ty = tid >> 4;
  const int lr = tid >> 4;
  const int lc = (tid & 15) << 2;

  const float* arow[4];
#pragma unroll
  for (int i = 0; i < 4; ++i) {
    int r = bm + lr + (i << 4);
    if (GATHER) {
      int src = gidx[(r & (B_ - 1)) * T_ + (r >> 7)];
      arow[i] = A + (size_t)src * K;
    } else {
      arow[i] = A + (size_t)r * K;
    }
  }

  float acc[4][4] = {};
  for (int k0 = 0; k0 < K; k0 += BK) {
#pragma unroll
    for (int i = 0; i < 4; ++i) {
      int rr = lr + (i << 4);
      float4 av = *(const float4*)(arow[i] + k0 + lc);
      As[lc + 0][rr] = av.x; As[lc + 1][rr] = av.y;
      As[lc + 2][rr] = av.z; As[lc + 3][rr] = av.w;
      float4 bv = *(const float4*)(Bw + (size_t)(bn + rr) * K + k0 + lc);
      Bs[lc + 0][rr] = bv.x; Bs[lc + 1][rr] = bv.y;
      Bs[lc + 2][rr] = bv.z; Bs[lc + 3][rr] = bv.w;
    }
    __syncthreads();
#pragma unroll 8
    for (int kk = 0; kk < BK; ++kk) {
      float4 a = *(const float4*)&As[kk][ty << 2];
      float4 b = *(const float4*)&Bs[kk][tx << 2];
      acc[0][0] += a.x * b.x; acc[0][1] += a.x * b.y; acc[0][2] += a.x * b.z; acc[0][3] += a.x * b.w;
      acc[1][0] += a.y * b.x; acc[1][1] += a.y * b.y; acc[1][2] += a.y * b.z; acc[1][3] += a.y * b.w;
      acc[2][0] += a.z * b.x; acc[2][1] += a.z * b.y; acc[2][2] += a.z * b.z; acc[2][3] += a.z * b.w;
      acc[3][0] += a.w * b.x; acc[3][1] += a.w * b.y; acc[3][2] += a.w * b.z; acc[3][3] += a.w * b.w;
    }
    __syncthreads();
  }

  float4 bb = *(const float4*)&bias[bn + (tx << 2)];
#pragma unroll
  for (int i = 0; i < 4; ++i) {
    int m = bm + (ty << 2) + i;
    float4 o;
    o.x = acc[i][0] + bb.x; o.y = acc[i][1] + bb.y;
    o.z = acc[i][2] + bb.z; o.w = acc[i][3] + bb.w;
    if (ACT == 1) {
      o.x = tanh_(o.x); o.y = tanh_(o.y); o.z = tanh_(o.z); o.w = tanh_(o.w);
    }
    *(float4*)&C[(size_t)m * N + bn + (tx << 2)] = o;
  }
}

// ---------------------------------------------------------------------------
// 512x512 transpose (W_word -> W_word^T)
// ---------------------------------------------------------------------------
__global__ __launch_bounds__(256) void transpose512(
    const float* __restrict__ in, float* __restrict__ out) {
  __shared__ float t[32][33];
  int bx = blockIdx.x * 32, by = blockIdx.y * 32;
  int c = (int)threadIdx.x & 31, r8 = (int)threadIdx.x >> 5;
#pragma unroll
  for (int i = 0; i < 4; ++i)
    t[r8 + i * 8][c] = in[(size_t)(by + r8 + i * 8) * 512 + bx + c];
  __syncthreads();
#pragma unroll
  for (int i = 0; i < 4; ++i)
    out[(size_t)(bx + r8 + i * 8) * 512 + by + c] = t[c][r8 + i * 8];
}

// ---------------------------------------------------------------------------
// Bidirectional GRU scan, v3 transport (r7).
// Geometry unchanged from r6: bid = quad*64 + dir*32 + bg; block owns
// 4 batches x 64 j x 3 gates; w_hh register-resident (192 f/thread);
// c-split workers + pscr reduce.
// NEW: FENCE-FREE exchange. All h-exchange traffic uses RELAXED agent-scope
// atomics (sc1: routed to the coherence point, bypassing the non-coherent
// per-XCD L2s). No __threadfence, no ACQUIRE — r6's 18.4us/step was
// attributed to the L2 writeback/invalidate those imply on gfx950.
// Producer ordering: s_waitcnt vmcnt(0) (h stores ack'd) + barrier + relaxed
// flag store. Consumer: relaxed polls, then relaxed u64 staging loads.
// WAR safety: partner posts flag[t] only after its staging LOADS of
// buffer[par] completed (vmcnt covers loads); t+1's producer overwrites
// buffer[par] only after seeing flag[t].
// ---------------------------------------------------------------------------
__global__ __launch_bounds__(256, 1) void gru_scan(
    const float* __restrict__ gi,        // [2][T][B][768]
    const float* __restrict__ w_hh_f, const float* __restrict__ w_hh_b,
    const float* __restrict__ b_hh_f, const float* __restrict__ b_hh_b,
    float* __restrict__ h_ex,            // [2 parity][2 dir][B][H]
    int* __restrict__ flg,               // [2*32 groups][4 quads][256]
    float* __restrict__ outw,            // [T*B][512]
    float* __restrict__ state_out)       // [2][B][H]
{
  __shared__ float hlds[4][256];         // 4KB: h for the group's 4 batches
  __shared__ float pscr[4][64][13];      // 13.3KB padded partials

  const int bid = (int)blockIdx.x;
  const int myq = bid >> 6;              // j-quad 0..3
  const int dgb = bid & 63;              // dir*32 + bg
  const int dir = dgb >> 5, bg = dgb & 31;
  const int tid = (int)threadIdx.x;
  const int lane = tid & 63;             // j within quad (worker & finalize)
  const int wv = tid >> 6;               // worker: c-quarter; finalize: batch
  const int jg = (myq << 6) + lane;      // global h index of this output
  const int gb = (bg << 2) + wv;         // finalize: global batch
  const float* whh = dir ? w_hh_b : w_hh_f;
  const float* bhh = dir ? b_hh_b : b_hh_f;

  // --- register w tile: rows g*H+jg, cols [wv*64, wv*64+64) ---
  float4 wr_[16], wz_[16], wn_[16];
  {
    const float* base_r = whh + (size_t)(0 * H_ + jg) * H_ + (wv << 6);
    const float* base_z = whh + (size_t)(1 * H_ + jg) * H_ + (wv << 6);
    const float* base_n = whh + (size_t)(2 * H_ + jg) * H_ + (wv << 6);
#pragma unroll
    for (int ci = 0; ci < 16; ++ci) {
      wr_[ci] = *(const float4*)(base_r + (ci << 2));
      wz_[ci] = *(const float4*)(base_z + (ci << 2));
      wn_[ci] = *(const float4*)(base_n + (ci << 2));
    }
  }
  const float bh_r = bhh[jg];
  const float bh_z = bhh[H_ + jg];
  const float bh_n = bhh[2 * H_ + jg];

  int* myflag   = flg + ((dgb << 2) + myq) * 256;
  int* pollflag = flg + ((dgb << 2) + ((myq + wv) & 3)) * 256;  // waves 1..3
  const size_t dirTB = (size_t)dir * T_ * B_;

  for (int t = 0; t < T_; ++t) {
    // --- wait for the 3 partner quads' h of step t-1 (parallel polls) ---
    if (t > 0 && wv > 0 && lane == 0) {
      while (__hip_atomic_load(&pollflag[t - 1], __ATOMIC_RELAXED,
                               __HIP_MEMORY_SCOPE_AGENT) == 0) {
        __builtin_amdgcn_s_sleep(1);
      }
    }
    __syncthreads();   // join polls

    const int par = t & 1;
    const float* hsrc = h_ex + ((size_t)(par * 2 + dir) * B_) * H_;
    // stage h[4 batches][256]: 2 relaxed u64 agent loads per thread
    // (sc1: reads the coherence point, never a stale L2 line)
    {
      const unsigned long long* hs64 =
          (const unsigned long long*)(hsrc + (size_t)(bg << 2) * H_);
      unsigned long long va = __hip_atomic_load(
          &hs64[tid * 2 + 0], __ATOMIC_RELAXED, __HIP_MEMORY_SCOPE_AGENT);
      unsigned long long vb = __hip_atomic_load(
          &hs64[tid * 2 + 1], __ATOMIC_RELAXED, __HIP_MEMORY_SCOPE_AGENT);
      unsigned long long* hd =
          (unsigned long long*)&hlds[tid >> 6][(tid & 63) << 2];
      hd[0] = va; hd[1] = vb;
    }
    // gi loads for this thread's output (gb, jg), consumed in finalize
    const int ta = dir ? (T_ - 1 - t) : t;
    const float* girow = gi + (dirTB + (size_t)ta * B_ + gb) * G3;
    const float gi_r = girow[jg];
    const float gi_z = girow[H_ + jg];
    const float gi_n = girow[2 * H_ + jg];
    __syncthreads();   // hlds ready

    // --- worker: partial dots over this wave's c-quarter, 4 batches ---
    float pr[4] = {0.f, 0.f, 0.f, 0.f};
    float pz[4] = {0.f, 0.f, 0.f, 0.f};
    float pn[4] = {0.f, 0.f, 0.f, 0.f};
#pragma unroll
    for (int ci = 0; ci < 16; ++ci) {
      const int co = (wv << 6) + (ci << 2);
      const float4 wr4 = wr_[ci];
      const float4 wz4 = wz_[ci];
      const float4 wn4 = wn_[ci];
#pragma unroll
      for (int k = 0; k < 4; ++k) {
        const float4 h4 = *(const float4*)&hlds[k][co];   // broadcast
        pr[k] += h4.x * wr4.x + h4.y * wr4.y + h4.z * wr4.z + h4.w * wr4.w;
        pz[k] += h4.x * wz4.x + h4.y * wz4.y + h4.z * wz4.z + h4.w * wz4.w;
        pn[k] += h4.x * wn4.x + h4.y * wn4.y + h4.z * wn4.z + h4.w * wn4.w;
      }
    }
#pragma unroll
    for (int k = 0; k < 4; ++k) {
      pscr[wv][lane][k]     = pr[k];
      pscr[wv][lane][4 + k] = pz[k];
      pscr[wv][lane][8 + k] = pn[k];
    }
    __syncthreads();   // partials ready

    // --- finalize: thread owns output (batch wv -> gb, j = lane -> jg) ---
    float ar = 0.f, az = 0.f, an = 0.f;
#pragma unroll
    for (int q = 0; q < 4; ++q) {
      ar += pscr[q][lane][wv];
      az += pscr[q][lane][4 + wv];
      an += pscr[q][lane][8 + wv];
    }
    const float hprev = hlds[wv][jg];
    const float r = sigmoid_(gi_r + ar + bh_r);
    const float z = sigmoid_(gi_z + az + bh_z);
    const float nv = tanh_(gi_n + r * (an + bh_n));
    const float hnew = (1.0f - z) * nv + z * hprev;

    float* hdst = h_ex + ((size_t)((par ^ 1) * 2 + dir) * B_) * H_;
    // publish h via relaxed agent store (sc1 write-through, no fence)
    __hip_atomic_store(&hdst[(size_t)gb * H_ + jg], hnew,
                       __ATOMIC_RELAXED, __HIP_MEMORY_SCOPE_AGENT);
    outw[((size_t)ta * B_ + gb) * 512 + dir * H_ + jg] = hnew;
    if (t == T_ - 1)
      state_out[(size_t)(dir * B_ + gb) * H_ + jg] = hnew;

    if (t < T_ - 1) {
      // order: my h stores ack'd -> barrier -> flag store (no cache ops)
      asm volatile("s_waitcnt vmcnt(0)" ::: "memory");
      __syncthreads();
      if (tid == 0) {
        __hip_atomic_store(&myflag[t], 1, __ATOMIC_RELAXED,
                           __HIP_MEMORY_SCOPE_AGENT);
      }
    }
  }
}

// ---------------------------------------------------------------------------
// logits[m] = squish[m][:512] . proj[:512]
// ---------------------------------------------------------------------------
__global__ __launch_bounds__(256) void logits_k(
    const float* __restrict__ squish, const float* __restrict__ proj,
    float* __restrict__ attn) {
  int wid = (int)threadIdx.x >> 6, lane = (int)threadIdx.x & 63;
  int m = (int)blockIdx.x * 4 + wid;
  const float* row = squish + (size_t)m * 512;
  int k = lane << 3;
  float4 a0 = *(const float4*)&row[k],  a1 = *(const float4*)&row[k + 4];
  float4 p0 = *(const float4*)&proj[k], p1 = *(const float4*)&proj[k + 4];
  float s = a0.x * p0.x + a0.y * p0.y + a0.z * p0.z + a0.w * p0.w +
            a1.x * p1.x + a1.y * p1.y + a1.z * p1.z + a1.w * p1.w;
#pragma unroll
  for (int o = 32; o; o >>= 1) s += __shfl_down(s, o);
  if (lane == 0) attn[m] = s;
}

// ---------------------------------------------------------------------------
// Per-batch softmax over T + weighted sum
// ---------------------------------------------------------------------------
__global__ __launch_bounds__(256) void attnsv_k(
    const float* __restrict__ logit, const float* __restrict__ outw,
    float* __restrict__ sent, float* __restrict__ attn_out) {
  __shared__ float red[256];
  __shared__ float wt[T_];
  const int b = (int)blockIdx.x, tid = (int)threadIdx.x;
  float lg = (tid < T_) ? logit[tid * B_ + b] : -INFINITY;
  red[tid] = lg; __syncthreads();
#pragma unroll
  for (int o = 128; o; o >>= 1) {
    if (tid < o) red[tid] = fmaxf(red[tid], red[tid + o]);
    __syncthreads();
  }
  float mx = red[0]; __syncthreads();
  float e = (tid < T_) ? __expf(lg - mx) : 0.0f;
  red[tid] = e; __syncthreads();
#pragma unroll
  for (int o = 128; o; o >>= 1) {
    if (tid < o) red[tid] += red[tid + o];
    __syncthreads();
  }
  float inv = 1.0f / red[0];
  if (tid < T_) {
    float w = e * inv;
    wt[tid] = w;
    attn_out[b * T_ + tid] = w;
  }
  __syncthreads();
  int c = tid * 2;
  float s0 = 0.f, s1 = 0.f;
  for (int t = 0; t < T_; ++t) {
    float w = wt[t];
    float2 v = *(const float2*)&outw[((size_t)t * B_ + b) * 512 + c];
    s0 += w * v.x; s1 += w * v.y;
  }
  *(float2*)&sent[b * 512 + c] = make_float2(s0, s1);
}

// ---------------------------------------------------------------------------
extern "C" void kernel_launch(void* const* d_in, const int* in_sizes, int n_in,
                              void* d_out, int out_size, void* d_ws, size_t ws_size,
                              hipStream_t stream) {
  const int*   ids     = (const int*)d_in[0];
  const float* state_w = (const float*)d_in[1];
  const float* emb     = (const float*)d_in[2];
  const float* w_ih_f  = (const float*)d_in[3];
  const float* w_hh_f  = (const float*)d_in[4];
  const float* b_ih_f  = (const float*)d_in[5];
  const float* b_hh_f  = (const float*)d_in[6];
  const float* w_ih_b  = (const float*)d_in[7];
  const float* w_hh_b  = (const float*)d_in[8];
  const float* b_ih_b  = (const float*)d_in[9];
  const float* b_hh_b  = (const float*)d_in[10];
  const float* W_word  = (const float*)d_in[11];
  const float* b_word  = (const float*)d_in[12];
  const float* proj    = (const float*)d_in[13];
  float* out = (float*)d_out;

  // Workspace layout (floats).
  float* w = (float*)d_ws;
  const size_t GI_DIR = (size_t)T_ * B_ * G3;         // 19,660,800
  float* gi     = w;                                  // [2][T][B][768]
  float* outw   = w + 2 * GI_DIR;                     // [T*B][512]
  float* wT     = outw + (size_t)T_ * B_ * 512;       // [512][512]
  float* h_ex   = wT + 512 * 512;                     // [2][2][B][H]
  int*   flg    = (int*)(h_ex + 2 * 2 * B_ * H_);     // [64 grp][4 q][256]
  float* logits = (float*)(flg + 64 * 4 * 256);       // [T*B]
  float* squish = w;                                  // alias over gi

  // init: zero flags (ws is 0xAA-poisoned each launch!), copy initial h
  (void)hipMemsetAsync(flg, 0, 64 * 4 * 256 * sizeof(int), stream);
  (void)hipMemcpyAsync(h_ex, state_w, 2 * B_ * H_ * sizeof(float),
                       hipMemcpyDeviceToDevice, stream);

  transpose512<<<dim3(16, 16), 256, 0, stream>>>(W_word, wT);

  gemm_nt<0, true><<<dim3(400, 12), 256, 0, stream>>>(
      emb, w_ih_f, b_ih_f, gi, T_ * B_, G3, E_, ids);
  gemm_nt<0, true><<<dim3(400, 12), 256, 0, stream>>>(
      emb, w_ih_b, b_ih_b, gi + GI_DIR, T_ * B_, G3, E_, ids);

  gru_scan<<<dim3(256), 256, 0, stream>>>(
      gi, w_hh_f, w_hh_b, b_hh_f, b_hh_b, h_ex, flg, outw,
      out + B_ * 512 /* state_out at offset 65536 */);

  gemm_nt<1, false><<<dim3(400, 8), 256, 0, stream>>>(
      outw, wT, b_word, squish, T_ * B_, 512, 512, nullptr);

  logits_k<<<dim3(6400), 256, 0, stream>>>(squish, proj, logits);

  attnsv_k<<<dim3(B_), 256, 0, stream>>>(
      logits, outw, out /* sent */, out + 2 * B_ * 512 /* attn */);

  (void)in_sizes; (void)n_in; (void)out_size; (void)ws_size;
}